// Round 19
// baseline (77.541 us; speedup 1.0000x reference)
//
#include <hip/hip_runtime.h>

#define IN_CH 64
#define OUT_CH 128
#define HW 128
#define KTAPS 9
#define LCOLS 80               // staged cols per row: 64 out + 2x8 halo
#define LROWB (LCOLS * 128)    // 10240 B per staged row (80 cols x 64 ic x 2B)

typedef __bf16 bf16x8 __attribute__((ext_vector_type(8)));
typedef float f32x16 __attribute__((ext_vector_type(16)));
typedef float f32x4 __attribute__((ext_vector_type(4)));

// fp32 -> bf16 round-to-nearest-even (data has no NaN/Inf) — prep use
__device__ __forceinline__ unsigned f2bf(float f) {
    unsigned u = __builtin_bit_cast(unsigned, f);
    return (u + 0x7FFFu + ((u >> 16) & 1u)) >> 16;
}

// HW packed f32x2 -> bf16x2 (RNE), 1 instruction (no builtin on gfx950)
__device__ __forceinline__ unsigned cvt_pk_bf16(float lo, float hi) {
    unsigned r;
    asm("v_cvt_pk_bf16_f32 %0, %1, %2" : "=v"(r) : "v"(lo), "v"(hi));
    return r;   // [15:0]=bf16(lo), [31:16]=bf16(hi)
}

// 16B-granule XOR swizzle keyed by local column (bits 4..6 of byte addr).
__device__ __forceinline__ int swz(int r) { return ((r ^ (r >> 3)) & 7) << 4; }

// W (OIHW fp32) -> Wl in wave-fragment order (PROVEN R9-R18):
// 16B chunk index = (p*9 + t)*512 + (m*4 + ks)*64 + lane
// Chunk content: 8 bf16 of A[oc = p*64+m*32+(lane&31)][ic = ks*16+(lane>>5)*8 ..+8].
__global__ void wprep_kernel(const float* __restrict__ W, unsigned short* __restrict__ Wl) {
    int i = blockIdx.x * blockDim.x + threadIdx.x;   // 73728 bf16 elements
    if (i >= OUT_CH * IN_CH * KTAPS) return;
    int p  = i / 36864;
    int r  = i % 36864;
    int t  = r >> 12;          // 0..8
    int r2 = r & 4095;
    int m  = r2 >> 11;
    int ks = (r2 >> 9) & 3;
    int l  = (r2 >> 3) & 63;
    int e  = r2 & 7;
    int oc = p * 64 + m * 32 + (l & 31);
    int ic = ks * 16 + (l >> 5) * 8 + e;
    int kh = t / 3, kw = t % 3;
    Wl[i] = (unsigned short)f2bf(W[((oc * IN_CH + ic) * 3 + kh) * 3 + kw]);
}

// Issue one tap's 4 A-fragment loads as volatile asm (compiler cannot sink
// them to their consumers). Base is per-lane; taps reached with imm offsets.
#define ISSUE_A(B0, B1, B2, B3, T) do {                                              \
    const char* _pp = (const char*)Ab + (T) * 8192;                                  \
    asm volatile("global_load_dwordx4 %0, %1, off"             : "=v"(B0) : "v"(_pp)); \
    asm volatile("global_load_dwordx4 %0, %1, off offset:1024" : "=v"(B1) : "v"(_pp)); \
    asm volatile("global_load_dwordx4 %0, %1, off offset:2048" : "=v"(B2) : "v"(_pp)); \
    asm volatile("global_load_dwordx4 %0, %1, off offset:3072" : "=v"(B3) : "v"(_pp)); \
} while (0)

// One tap's compute: counted vmcnt wait (never 0 until the last tap) +
// sched_barrier(0) fence (rule #18), then 8 swizzled ds_read_b128 + 8 MFMAs.
// Local columns: lc = l31 + 8*kw (+32) in [0,80) — halo absorbs the wrap.
#define TAP_BODY(A0_, A1_, A2_, A3_, T, WAITSTR) do {                                \
    constexpr int _kh = (T) / 3, _kw = (T) % 3;                                      \
    int _xc0 = l31 + 8 * _kw;                                                        \
    int _xc1 = _xc0 + 32;                                                            \
    int _b0 = _kh * LROWB + _xc0 * 128 + lhi * 16, _s0 = swz(_xc0);                  \
    int _b1 = _kh * LROWB + _xc1 * 128 + lhi * 16, _s1 = swz(_xc1);                  \
    asm volatile(WAITSTR);                                                           \
    __builtin_amdgcn_sched_barrier(0);                                               \
    const bf16x8 _A[4] = {A0_, A1_, A2_, A3_};                                       \
    _Pragma("unroll")                                                                \
    for (int ks = 0; ks < 4; ++ks) {                                                 \
        bf16x8 _vb0 = *reinterpret_cast<const bf16x8*>(xsB + ((_b0 + ks * 32) ^ _s0)); \
        bf16x8 _vb1 = *reinterpret_cast<const bf16x8*>(xsB + ((_b1 + ks * 32) ^ _s1)); \
        acc[0] = __builtin_amdgcn_mfma_f32_32x32x16_bf16(_A[ks], _vb0, acc[0], 0, 0, 0); \
        acc[1] = __builtin_amdgcn_mfma_f32_32x32x16_bf16(_A[ks], _vb1, acc[1], 0, 0, 0); \
    }                                                                                \
} while (0)

// Fused conv, w-half blocks: 4096 blocks x 256 threads (4 waves). Each wave =
// 32oc x 64w (proven shape) with R14's asm counted-vmcnt A-pipeline verbatim.
// LDS padded to 40KB -> EXACTLY 4 blocks/CU: 16 sequential blocks pack as 4x4
// (no drain tail) and each SIMD hosts 4 waves from 4 DIFFERENT blocks at
// independent phases — staging/compute/store mix at SIMD level.
__global__ __launch_bounds__(256, 4) void conv_kernel_f(
    const float* __restrict__ x, const unsigned short* __restrict__ Wl,
    const float* __restrict__ bias, float* __restrict__ y)
{
    __shared__ __align__(16) unsigned char xsB[40960];   // 30720 used; pad -> 4 blocks/CU

    int bid = blockIdx.x;                      // 4096 blocks
    int sb  = (bid & 7) * 512 + (bid >> 3);    // XCD swizzle (bijective: 4096 = 8*512)
    int half = sb & 1;
    int h    = (sb >> 1) & 127;
    int n    = sb >> 8;
    int w0   = half * 64;
    int tid  = threadIdx.x;
    int wid  = tid >> 6, lane = tid & 63;
    int l31 = lane & 31, lhi = lane >> 5;

    // wave role: oc quarter pm = wid (p = wid>>1, m = wid&1); full 64-w span.
    const bf16x8* Ab = reinterpret_cast<const bf16x8*>(Wl)
                     + (wid >> 1) * (9 * 512) + (wid & 1) * 256 + lane;

    // tap-0 A loads issued FIRST (asm, cannot sink): fly under all of staging;
    // the staging barrier's vmcnt(0) drain guarantees they're ready for tap 0.
    bf16x8 aE0, aE1, aE2, aE3, aO0, aO1, aO2, aO3;
    ISSUE_A(aE0, aE1, aE2, aE3, 0);

    // ---- stage 3 rows x 80 cols: 960 quarter-groups (row, c4, ic4);
    //      per group 4 float4 loads (4 ic x 4 w), 8 cvt_pk, 4 b64 writes.
    //      Global col g = (w0 - 8 + lc) & 127; groups are 4-aligned so the
    //      circular wrap never splits a float4.
    for (int q = tid; q < 960; q += 256) {
        int ic4 = q & 15;
        int c5  = q >> 4;          // 0..59
        int c4  = c5 % 20;
        int row = c5 / 20;         // 0..2
        int srow = (h + row * 8 + 120) & 127;       // h-8, h, h+8 (mod 128)
        int g4   = (w0 - 8 + c4 * 4) & 127;         // aligned global col group
        const float* xp = x + (((n * IN_CH + ic4 * 4) * HW + srow) * HW + g4);
        f32x4 v[4];
        #pragma unroll
        for (int j = 0; j < 4; ++j)
            v[j] = *reinterpret_cast<const f32x4*>(xp + j * (HW * HW));
        #pragma unroll
        for (int j2 = 0; j2 < 4; ++j2) {
            int lc = c4 * 4 + j2;                   // local col 0..79
            uint2 pk;
            pk.x = cvt_pk_bf16(v[0][j2], v[1][j2]);
            pk.y = cvt_pk_bf16(v[2][j2], v[3][j2]);
            *reinterpret_cast<uint2*>(xsB + row * LROWB + ((lc * 128 + ic4 * 8) ^ swz(lc))) = pk;
        }
    }
    __syncthreads();   // the ONLY barrier (drains staging + tap-0 A loads)

    f32x16 acc[2];
    #pragma unroll
    for (int bq = 0; bq < 2; ++bq)
        #pragma unroll
        for (int r = 0; r < 16; ++r) acc[bq][r] = 0.0f;

    // ---- K-loop: asm double-buffered A, counted vmcnt(4), one-tap lookahead.
    ISSUE_A(aO0, aO1, aO2, aO3, 1);
    TAP_BODY(aE0, aE1, aE2, aE3, 0, "s_waitcnt vmcnt(4)");
    ISSUE_A(aE0, aE1, aE2, aE3, 2);
    TAP_BODY(aO0, aO1, aO2, aO3, 1, "s_waitcnt vmcnt(4)");
    ISSUE_A(aO0, aO1, aO2, aO3, 3);
    TAP_BODY(aE0, aE1, aE2, aE3, 2, "s_waitcnt vmcnt(4)");
    ISSUE_A(aE0, aE1, aE2, aE3, 4);
    TAP_BODY(aO0, aO1, aO2, aO3, 3, "s_waitcnt vmcnt(4)");
    ISSUE_A(aO0, aO1, aO2, aO3, 5);
    TAP_BODY(aE0, aE1, aE2, aE3, 4, "s_waitcnt vmcnt(4)");
    ISSUE_A(aE0, aE1, aE2, aE3, 6);
    TAP_BODY(aO0, aO1, aO2, aO3, 5, "s_waitcnt vmcnt(4)");
    ISSUE_A(aO0, aO1, aO2, aO3, 7);
    TAP_BODY(aE0, aE1, aE2, aE3, 6, "s_waitcnt vmcnt(4)");
    ISSUE_A(aE0, aE1, aE2, aE3, 8);
    TAP_BODY(aO0, aO1, aO2, aO3, 7, "s_waitcnt vmcnt(4)");
    TAP_BODY(aE0, aE1, aE2, aE3, 8, "s_waitcnt vmcnt(0)");

    // ---- epilogue: bias + store. D: col=l31(w), row=(reg&3)+8*(reg>>2)+4*lhi ----
    int outbase = (n * OUT_CH) * HW * HW + h * HW;
    #pragma unroll
    for (int bq = 0; bq < 2; ++bq) {
        int wcol = w0 + bq * 32 + l31;
        #pragma unroll
        for (int reg = 0; reg < 16; ++reg) {
            int oc = wid * 32 + (reg & 3) + 8 * (reg >> 2) + 4 * lhi;
            y[outbase + oc * HW * HW + wcol] = acc[bq][reg] + bias[oc];
        }
    }
}

extern "C" void kernel_launch(void* const* d_in, const int* in_sizes, int n_in,
                              void* d_out, int out_size, void* d_ws, size_t ws_size,
                              hipStream_t stream) {
    const float* x = (const float*)d_in[0];
    const float* W = (const float*)d_in[1];
    const float* b = (const float*)d_in[2];
    float* y = (float*)d_out;

    unsigned short* Wl = (unsigned short*)d_ws;   // 147456 B

    hipLaunchKernelGGL(wprep_kernel, dim3((OUT_CH * IN_CH * KTAPS + 255) / 256), dim3(256), 0, stream, W, Wl);
    hipLaunchKernelGGL(conv_kernel_f, dim3(4096), dim3(256), 0, stream, x, Wl, b, y);
}

// Round 20
// 61.139 us; speedup vs baseline: 1.2683x; 1.2683x over previous
//
#include <hip/hip_runtime.h>

#define IN_CH 64
#define OUT_CH 128
#define HW 128
#define KTAPS 9
#define ROWB 16384             // bytes per staged row image: 128 w * 64 ic * 2B

typedef __bf16 bf16x8 __attribute__((ext_vector_type(8)));
typedef float f32x16 __attribute__((ext_vector_type(16)));
typedef float f32x4 __attribute__((ext_vector_type(4)));

// fp32 -> bf16 round-to-nearest-even (data has no NaN/Inf) — prep use
__device__ __forceinline__ unsigned f2bf(float f) {
    unsigned u = __builtin_bit_cast(unsigned, f);
    return (u + 0x7FFFu + ((u >> 16) & 1u)) >> 16;
}

// HW packed f32x2 -> bf16x2 (RNE), 1 instruction (no builtin on gfx950)
__device__ __forceinline__ unsigned cvt_pk_bf16(float lo, float hi) {
    unsigned r;
    asm("v_cvt_pk_bf16_f32 %0, %1, %2" : "=v"(r) : "v"(lo), "v"(hi));
    return r;   // [15:0]=bf16(lo), [31:16]=bf16(hi)
}

// 16B-granule XOR swizzle keyed by row (3 bits -> byte-addr bits 4..6).
__device__ __forceinline__ int swz(int r) { return ((r ^ (r >> 3)) & 7) << 4; }

// W (OIHW fp32) -> Wl in wave-fragment order (PROVEN R9-R19):
// 16B chunk index = (p*9 + t)*512 + (m*4 + ks)*64 + lane
// Chunk content: 8 bf16 of A[oc = p*64+m*32+(lane&31)][ic = ks*16+(lane>>5)*8 ..+8].
__global__ void wprep_kernel(const float* __restrict__ W, unsigned short* __restrict__ Wl) {
    int i = blockIdx.x * blockDim.x + threadIdx.x;   // 73728 bf16 elements
    if (i >= OUT_CH * IN_CH * KTAPS) return;
    int p  = i / 36864;
    int r  = i % 36864;
    int t  = r >> 12;          // 0..8
    int r2 = r & 4095;
    int m  = r2 >> 11;
    int ks = (r2 >> 9) & 3;
    int l  = (r2 >> 3) & 63;
    int e  = r2 & 7;
    int oc = p * 64 + m * 32 + (l & 31);
    int ic = ks * 16 + (l >> 5) * 8 + e;
    int kh = t / 3, kw = t % 3;
    Wl[i] = (unsigned short)f2bf(W[((oc * IN_CH + ic) * 3 + kh) * 3 + kw]);
}

// Issue one tap's 4 A-fragment loads as volatile asm (compiler cannot sink
// them to their consumers). Base is per-lane; taps reached with imm offsets.
#define ISSUE_A(B0, B1, B2, B3, T) do {                                              \
    const char* _pp = (const char*)Ab + (T) * 8192;                                  \
    asm volatile("global_load_dwordx4 %0, %1, off"             : "=v"(B0) : "v"(_pp)); \
    asm volatile("global_load_dwordx4 %0, %1, off offset:1024" : "=v"(B1) : "v"(_pp)); \
    asm volatile("global_load_dwordx4 %0, %1, off offset:2048" : "=v"(B2) : "v"(_pp)); \
    asm volatile("global_load_dwordx4 %0, %1, off offset:3072" : "=v"(B3) : "v"(_pp)); \
} while (0)

// One tap's compute: counted vmcnt wait (never 0 until the last tap) +
// sched_barrier(0) fence (rule #18), then 8 swizzled ds_read_b128 + 8 MFMAs.
#define TAP_BODY(A0_, A1_, A2_, A3_, T, WAITSTR) do {                                \
    constexpr int _kh = (T) / 3, _kw = (T) % 3;                                      \
    int _xc0 = (wc * 64 + l31 + 8 * _kw - 8) & 127;                                  \
    int _xc1 = (_xc0 + 32) & 127;                                                    \
    int _b0 = _kh * ROWB + _xc0 * 128 + lhi * 16, _s0 = swz(_xc0);                   \
    int _b1 = _kh * ROWB + _xc1 * 128 + lhi * 16, _s1 = swz(_xc1);                   \
    asm volatile(WAITSTR);                                                           \
    __builtin_amdgcn_sched_barrier(0);                                               \
    const bf16x8 _A[4] = {A0_, A1_, A2_, A3_};                                       \
    _Pragma("unroll")                                                                \
    for (int ks = 0; ks < 4; ++ks) {                                                 \
        bf16x8 _vb0 = *reinterpret_cast<const bf16x8*>(xsB + ((_b0 + ks * 32) ^ _s0)); \
        bf16x8 _vb1 = *reinterpret_cast<const bf16x8*>(xsB + ((_b1 + ks * 32) ^ _s1)); \
        acc[0] = __builtin_amdgcn_mfma_f32_32x32x16_bf16(_A[ks], _vb0, acc[0], 0, 0, 0); \
        acc[1] = __builtin_amdgcn_mfma_f32_32x32x16_bf16(_A[ks], _vb1, acc[1], 0, 0, 0); \
    }                                                                                \
} while (0)

// Fused conv (session best, R14/R18): 512 threads / 8 thin waves (32oc x 64w,
// acc=32) per (n,h); B staged once (cvt_pk, balanced, swizzled); A streamed
// from L2-resident Wl through an asm counted-vmcnt double-buffer pipeline.
__global__ __launch_bounds__(512, 5) void conv_kernel_f(
    const float* __restrict__ x, const unsigned short* __restrict__ Wl,
    const float* __restrict__ bias, float* __restrict__ y)
{
    __shared__ __align__(16) unsigned char xsB[3 * ROWB];   // 48 KiB -> 3 blocks/CU

    int bid = blockIdx.x;
    int sb  = (bid & 7) * 256 + (bid >> 3);   // XCD-contiguous h ranges (bijective: 2048 = 8*256)
    int n = sb >> 7, h = sb & 127;
    int tid = threadIdx.x;
    int wid = tid >> 6, lane = tid & 63;

    // wave roles: wr = oc quarter (32 rows), wc = w half (64 cols)
    int wr = wid >> 1, wc = wid & 1;
    int l31 = lane & 31, lhi = lane >> 5;
    int p = wr >> 1, m = wr & 1;

    // A chunk pointer (16B units): proven fragment order, quarter-selected.
    const bf16x8* Ab = reinterpret_cast<const bf16x8*>(Wl)
                     + p * (9 * 512) + m * 256 + lane;

    // tap-0 A loads issued FIRST (asm, cannot sink): fly under all of staging;
    // the staging barrier's vmcnt(0) drain guarantees they're ready for tap 0.
    bf16x8 aE0, aE1, aE2, aE3, aO0, aO1, aO2, aO3;
    ISSUE_A(aE0, aE1, aE2, aE3, 0);

    // ---- stage 3 B-rows (h-8, h, h+8): 1536 quarter-groups (kh, ic4, w4),
    //      exactly 3 per thread; 4 float4 loads -> 8 cvt_pk -> 4 b64 writes.
    #pragma unroll
    for (int g = 0; g < 3; ++g) {
        int q   = g * 512 + tid;     // 0..1535
        int w4  = q & 31;
        int ic4 = (q >> 5) & 15;
        int kh  = q >> 9;
        int srow = (h + kh * 8 + 120) & 127;   // h-8, h, h+8 (mod 128)
        const float* xp = x + (((n * IN_CH + ic4 * 4) * HW + srow) * HW + w4 * 4);
        f32x4 v[4];
        #pragma unroll
        for (int j = 0; j < 4; ++j)
            v[j] = *reinterpret_cast<const f32x4*>(xp + j * (HW * HW));
        #pragma unroll
        for (int j2 = 0; j2 < 4; ++j2) {
            int w = w4 * 4 + j2;
            uint2 pk;
            pk.x = cvt_pk_bf16(v[0][j2], v[1][j2]);
            pk.y = cvt_pk_bf16(v[2][j2], v[3][j2]);
            *reinterpret_cast<uint2*>(xsB + kh * ROWB + ((w * 128 + ic4 * 8) ^ swz(w))) = pk;
        }
    }
    __syncthreads();   // the ONLY barrier (drains staging + tap-0 A loads)

    f32x16 acc[2];
    #pragma unroll
    for (int bq = 0; bq < 2; ++bq)
        #pragma unroll
        for (int r = 0; r < 16; ++r) acc[bq][r] = 0.0f;

    // ---- K-loop: asm double-buffered A, counted vmcnt(4), one-tap lookahead.
    // Steady state keeps 4-8 loads in flight; never drains to 0 until t=8.
    ISSUE_A(aO0, aO1, aO2, aO3, 1);
    TAP_BODY(aE0, aE1, aE2, aE3, 0, "s_waitcnt vmcnt(4)");
    ISSUE_A(aE0, aE1, aE2, aE3, 2);
    TAP_BODY(aO0, aO1, aO2, aO3, 1, "s_waitcnt vmcnt(4)");
    ISSUE_A(aO0, aO1, aO2, aO3, 3);
    TAP_BODY(aE0, aE1, aE2, aE3, 2, "s_waitcnt vmcnt(4)");
    ISSUE_A(aE0, aE1, aE2, aE3, 4);
    TAP_BODY(aO0, aO1, aO2, aO3, 3, "s_waitcnt vmcnt(4)");
    ISSUE_A(aO0, aO1, aO2, aO3, 5);
    TAP_BODY(aE0, aE1, aE2, aE3, 4, "s_waitcnt vmcnt(4)");
    ISSUE_A(aE0, aE1, aE2, aE3, 6);
    TAP_BODY(aO0, aO1, aO2, aO3, 5, "s_waitcnt vmcnt(4)");
    ISSUE_A(aO0, aO1, aO2, aO3, 7);
    TAP_BODY(aE0, aE1, aE2, aE3, 6, "s_waitcnt vmcnt(4)");
    ISSUE_A(aE0, aE1, aE2, aE3, 8);
    TAP_BODY(aO0, aO1, aO2, aO3, 7, "s_waitcnt vmcnt(4)");
    TAP_BODY(aE0, aE1, aE2, aE3, 8, "s_waitcnt vmcnt(0)");

    // ---- epilogue: bias + store. D: col=l31(w), row=(reg&3)+8*(reg>>2)+4*lhi ----
    int outbase = (n * OUT_CH) * HW * HW + h * HW;
    #pragma unroll
    for (int bq = 0; bq < 2; ++bq) {
        int wcol = wc * 64 + bq * 32 + l31;
        #pragma unroll
        for (int reg = 0; reg < 16; ++reg) {
            int oc = wr * 32 + (reg & 3) + 8 * (reg >> 2) + 4 * lhi;
            y[outbase + oc * HW * HW + wcol] = acc[bq][reg] + bias[oc];
        }
    }
}

extern "C" void kernel_launch(void* const* d_in, const int* in_sizes, int n_in,
                              void* d_out, int out_size, void* d_ws, size_t ws_size,
                              hipStream_t stream) {
    const float* x = (const float*)d_in[0];
    const float* W = (const float*)d_in[1];
    const float* b = (const float*)d_in[2];
    float* y = (float*)d_out;

    unsigned short* Wl = (unsigned short*)d_ws;   // 147456 B

    hipLaunchKernelGGL(wprep_kernel, dim3((OUT_CH * IN_CH * KTAPS + 255) / 256), dim3(256), 0, stream, W, Wl);
    hipLaunchKernelGGL(conv_kernel_f, dim3(16 * HW), dim3(512), 0, stream, x, Wl, b, y);
}